// Round 1
// baseline (1092.811 us; speedup 1.0000x reference)
//
#include <hip/hip_runtime.h>

// ScaledDotProductAttention: B=2,H=16,L=2048,D=128, fp32 in, outputs (x, attn_weight) fp32.
// R3: register-prefetch pipeline (T14). K/V global loads for tile t+1 are issued during the
// staging phase of tile t and stay in flight across the compute phase. Barriers are raw
// s_barrier (sched_barrier(0) + s_waitcnt lgkmcnt(0) + s_barrier + sched_barrier(0)) so the
// prefetch is NOT drained by a vmcnt(0) (the __syncthreads barrier-drain was the stall:
// MfmaUtil 9.8%, VALUBusy 21%, HBM 27% -> ~70% of cycles idle on vmem latency).
// Math identical to R2 (bit-exact outputs).

typedef __attribute__((ext_vector_type(8))) __bf16 bf16x8;
typedef __attribute__((ext_vector_type(4))) float f32x4;

#define L_SEQ 2048
#define D_H   128
#define R_Q   128     // q rows per block
#define C_K   64      // keys per k-tile
#define NTHR  512     // 8 waves
#define KPITCH 136    // shorts; 272 B row stride = 68 dwords (odd*4 -> conflict-free b128 reads)
#define VPITCH 72     // shorts; 144 B row stride
#define NKT   (L_SEQ / C_K)

__device__ __forceinline__ unsigned short f2bf(float f) {
    unsigned int u = __float_as_uint(f);
    unsigned int r = (u + 0x7FFFu + ((u >> 16) & 1u)) >> 16;  // RNE
    return (unsigned short)r;
}

__device__ __forceinline__ float fexp2(float x) {
#if __has_builtin(__builtin_amdgcn_exp2f)
    return __builtin_amdgcn_exp2f(x);
#else
    return exp2f(x);
#endif
}

__device__ __forceinline__ float rsum16(float v) {
#pragma unroll
    for (int o = 1; o < 16; o <<= 1) v += __shfl_xor(v, o, 64);
    return v;
}

// Raw workgroup barrier with LDS visibility but WITHOUT vmcnt drain:
// - sched_barrier(0) pins all prior ds_writes before the lgkmcnt wait
// - s_waitcnt lgkmcnt(0) makes this wave's LDS writes visible
// - s_barrier syncs waves; trailing sched_barrier(0) keeps later ds_reads after it.
// Outstanding global loads/stores (vmcnt) survive the barrier -> prefetch overlap.
__device__ __forceinline__ void block_sync() {
    __builtin_amdgcn_sched_barrier(0);
    asm volatile("s_waitcnt lgkmcnt(0)");
    __builtin_amdgcn_s_barrier();
    __builtin_amdgcn_sched_barrier(0);
}

union BF8 {
    bf16x8 v;
    unsigned short s[8];
    uint4 u;
};

__global__ __launch_bounds__(NTHR, 4) void attn_kernel(
    const float* __restrict__ Q, const float* __restrict__ K,
    const float* __restrict__ V, const float* __restrict__ mask,
    const int* __restrict__ pad, float* __restrict__ Xout,
    float* __restrict__ Pout)
{
    __shared__ unsigned short Ks[C_K * KPITCH];   // 17408 B
    __shared__ unsigned short Vt[D_H * VPITCH];   // 18432 B (V transposed: [d][key])
    __shared__ unsigned short Ps[R_Q * VPITCH];   // 18432 B (wave-local C/D->A hop)
    __shared__ float PadB[L_SEQ];                 //  8192 B (0 or -inf)
    // total 62464 B -> 2 blocks/CU

    const int tid  = threadIdx.x;
    const int wave = tid >> 6;
    const int lane = tid & 63;
    const int quad = lane >> 4;
    const int l16  = lane & 15;

    const int bh = blockIdx.x & 31;   // same bh -> same XCD group for K/V L2 locality
    const int qt = blockIdx.x >> 5;
    const int b  = bh >> 4;

    const float LOG2E  = 1.44269504088896340736f;
    const float SCALE2 = 0.08838834764831845f * 1.44269504088896340736f;  // (1/sqrt(128))*log2e

    const float* Kg0 = K + (long long)bh * L_SEQ * D_H;
    const float* Vg0 = V + (long long)bh * L_SEQ * D_H;

    // ---- Q fragments straight to registers (A-layout: row=wave*16+l16, k=kb*32+quad*8+j) ----
    BF8 qf[4];
    {
        const float4* qrow = reinterpret_cast<const float4*>(
            Q + ((long long)bh * L_SEQ + qt * R_Q + wave * 16 + l16) * D_H);
#pragma unroll
        for (int kb = 0; kb < 4; ++kb) {
            float4 a = qrow[kb * 8 + quad * 2];
            float4 c = qrow[kb * 8 + quad * 2 + 1];
            qf[kb].s[0] = f2bf(a.x); qf[kb].s[1] = f2bf(a.y);
            qf[kb].s[2] = f2bf(a.z); qf[kb].s[3] = f2bf(a.w);
            qf[kb].s[4] = f2bf(c.x); qf[kb].s[5] = f2bf(c.y);
            qf[kb].s[6] = f2bf(c.z); qf[kb].s[7] = f2bf(c.w);
        }
    }
    // ---- padding bias (0 / -inf) ----
#pragma unroll
    for (int i = 0; i < 4; ++i) {
        int idx = tid + i * NTHR;
        PadB[idx] = pad[b * L_SEQ + idx] ? -INFINITY : 0.0f;
    }

    // ---- prefetch registers: tile t+1 loads live across the compute phase of tile t ----
    float4 kpre[4];    // 16 VGPR
    float  vpre[16];   // 16 VGPR

    auto issueK = [&](int kt) {
        const float4* Kg = reinterpret_cast<const float4*>(Kg0 + (long long)kt * C_K * D_H);
#pragma unroll
        for (int i = 0; i < 2; ++i) {
            int c = tid + i * NTHR;          // 8-float chunk id, 1024 total
            kpre[2 * i]     = Kg[c * 2];
            kpre[2 * i + 1] = Kg[c * 2 + 1];
        }
    };
    auto writeK = [&]() {
#pragma unroll
        for (int i = 0; i < 2; ++i) {
            int c = tid + i * NTHR;
            int row = c >> 4, off = (c & 15) * 8;
            float4 a = kpre[2 * i];
            float4 d = kpre[2 * i + 1];
            BF8 t;
            t.s[0] = f2bf(a.x); t.s[1] = f2bf(a.y); t.s[2] = f2bf(a.z); t.s[3] = f2bf(a.w);
            t.s[4] = f2bf(d.x); t.s[5] = f2bf(d.y); t.s[6] = f2bf(d.z); t.s[7] = f2bf(d.w);
            *reinterpret_cast<uint4*>(&Ks[row * KPITCH + off]) = t.u;   // 16B write
        }
    };
    auto issueV = [&](int kt) {
        const float* Vg = Vg0 + (long long)kt * C_K * D_H;
        int c = tid & 127;
#pragma unroll
        for (int i = 0; i < 2; ++i) {
            int key0 = (((tid >> 7) + i * 4) << 3);
#pragma unroll
            for (int j = 0; j < 8; ++j)
                vpre[i * 8 + j] = Vg[(key0 + j) * D_H + c];   // coalesced across lanes
        }
    };
    auto writeV = [&]() {
        int c = tid & 127;
#pragma unroll
        for (int i = 0; i < 2; ++i) {
            int key0 = (((tid >> 7) + i * 4) << 3);
            BF8 t;
#pragma unroll
            for (int j = 0; j < 8; ++j) t.s[j] = f2bf(vpre[i * 8 + j]);
            *reinterpret_cast<uint4*>(&Vt[c * VPITCH + key0]) = t.u;
        }
    };

    auto computeS = [&](f32x4* sacc) {
        f32x4 z4 = {0.f, 0.f, 0.f, 0.f};
#pragma unroll
        for (int ct = 0; ct < 4; ++ct) sacc[ct] = z4;
#pragma unroll
        for (int kb = 0; kb < 4; ++kb) {
#pragma unroll
            for (int ct = 0; ct < 4; ++ct) {
                bf16x8 bk = *reinterpret_cast<const bf16x8*>(
                    &Ks[(ct * 16 + l16) * KPITCH + kb * 32 + quad * 8]);
                sacc[ct] = __builtin_amdgcn_mfma_f32_16x16x32_bf16(qf[kb].v, bk, sacc[ct], 0, 0, 0);
            }
        }
    };

    // lane owns rows (quad*4 + r), r=0..3 (replicated over the 16 lanes of its quad)
    const long long qrow0 = (long long)(qt * R_Q + wave * 16 + quad * 4);
    const float* maskBase = mask + qrow0 * L_SEQ;

    // =================== PASS 1: row sums of exp2(e2) ===================
    float lpart[4] = {0.f, 0.f, 0.f, 0.f};
    issueK(0);
    for (int kt = 0; kt < NKT; ++kt) {
        block_sync();                 // waves done reading Ks of tile kt-1 (no vmcnt drain)
        writeK();                     // compiler waits vmcnt for kpre here
        if (kt + 1 < NKT) issueK(kt + 1);   // in flight across compute phase
        block_sync();
        // mask + pad loads first: global latency hides under the MFMAs below
        float mk[4][4], pb[4];
#pragma unroll
        for (int ct = 0; ct < 4; ++ct) {
            int kc = kt * C_K + ct * 16 + l16;
            pb[ct] = PadB[kc];
#pragma unroll
            for (int r = 0; r < 4; ++r) mk[ct][r] = maskBase[(long long)r * L_SEQ + kc];
        }
        f32x4 sacc[4];
        computeS(sacc);
#pragma unroll
        for (int ct = 0; ct < 4; ++ct)
#pragma unroll
            for (int r = 0; r < 4; ++r) {
                float m2 = fmaf(mk[ct][r], LOG2E, pb[ct]);          // -inf if padded
                float e2 = fmaf(sacc[ct][r], SCALE2, m2);
                lpart[r] += fexp2(e2);                              // exp2(-inf)=0
            }
    }

    float rinv[4];
#pragma unroll
    for (int r = 0; r < 4; ++r) {
        float l = rsum16(lpart[r]);
        rinv[r] = (l > 0.f) ? (1.0f / l) : 0.f;
    }

    // =================== PASS 2: write P, accumulate O = P @ V ===================
    f32x4 oacc[8];
    {
        f32x4 z4 = {0.f, 0.f, 0.f, 0.f};
#pragma unroll
        for (int ct = 0; ct < 8; ++ct) oacc[ct] = z4;
    }
    float* PoutBase = Pout + ((long long)bh * L_SEQ + (qt * R_Q + wave * 16 + quad * 4)) * L_SEQ;

    issueK(0);
    issueV(0);
    for (int kt = 0; kt < NKT; ++kt) {
        block_sync();                 // waves done reading Ks/Vt of tile kt-1
        writeK();
        writeV();
        if (kt + 1 < NKT) { issueK(kt + 1); issueV(kt + 1); }
        block_sync();
        float mk[4][4], pb[4];
#pragma unroll
        for (int ct = 0; ct < 4; ++ct) {
            int kc = kt * C_K + ct * 16 + l16;
            pb[ct] = PadB[kc];
#pragma unroll
            for (int r = 0; r < 4; ++r) mk[ct][r] = maskBase[(long long)r * L_SEQ + kc];
        }
        f32x4 sacc[4];
        computeS(sacc);
#pragma unroll
        for (int ct = 0; ct < 4; ++ct) {
            int kc = kt * C_K + ct * 16 + l16;
#pragma unroll
            for (int r = 0; r < 4; ++r) {
                float m2 = fmaf(mk[ct][r], LOG2E, pb[ct]);
                float e2 = fmaf(sacc[ct][r], SCALE2, m2);
                float p  = fexp2(e2) * rinv[r];
                __builtin_nontemporal_store(p, &PoutBase[(long long)r * L_SEQ + kc]);
                Ps[(wave * 16 + quad * 4 + r) * VPITCH + ct * 16 + l16] = f2bf(p);
            }
        }
        // NO barrier: Ps rows [wave*16, wave*16+16) are written and read by the same wave;
        // in-wave DS ordering + compiler lgkmcnt handles the RAW.
#pragma unroll
        for (int kd = 0; kd < 2; ++kd) {
            bf16x8 ap = *reinterpret_cast<const bf16x8*>(
                &Ps[(wave * 16 + l16) * VPITCH + kd * 32 + quad * 8]);
#pragma unroll
            for (int ct = 0; ct < 8; ++ct) {
                bf16x8 bv = *reinterpret_cast<const bf16x8*>(
                    &Vt[(ct * 16 + l16) * VPITCH + kd * 32 + quad * 8]);
                oacc[ct] = __builtin_amdgcn_mfma_f32_16x16x32_bf16(ap, bv, oacc[ct], 0, 0, 0);
            }
        }
    }

    // epilogue: O rows = quad*4+r, cols = ct*16+l16
    float* Xg = Xout + ((long long)bh * L_SEQ + qt * R_Q + wave * 16 + quad * 4) * D_H;
#pragma unroll
    for (int ct = 0; ct < 8; ++ct)
#pragma unroll
        for (int r = 0; r < 4; ++r)
            __builtin_nontemporal_store(oacc[ct][r], &Xg[r * D_H + ct * 16 + l16]);
}

extern "C" void kernel_launch(void* const* d_in, const int* in_sizes, int n_in,
                              void* d_out, int out_size, void* d_ws, size_t ws_size,
                              hipStream_t stream) {
    const float* Q    = (const float*)d_in[0];
    const float* K    = (const float*)d_in[1];
    const float* V    = (const float*)d_in[2];
    const float* mask = (const float*)d_in[3];
    const int*   pad  = (const int*)d_in[4];   // bool input -> int32 per harness dtype rules
    float* Xout = (float*)d_out;
    float* Pout = (float*)d_out + (long long)2 * 16 * 2048 * 128;  // x first, then attn weights
    attn_kernel<<<dim3(512), dim3(NTHR), 0, stream>>>(Q, K, V, mask, pad, Xout, Pout);
}

// Round 2
// 888.323 us; speedup vs baseline: 1.2302x; 1.2302x over previous
//
#include <hip/hip_runtime.h>

// ScaledDotProductAttention: B=2,H=16,L=2048,D=128, fp32 in, outputs (x, attn_weight) fp32.
// R4: T14 async-STAGE done right. Iteration = {syncA; issue loads(t+1); compute(t); syncB;
// cvt+write(t+1)}. Prefetch regs live across ONE barrier with the compute phase as latency
// cover (R3 crossed two barriers + compute -> allocator spilled at 64 VGPR, +1.1GB scratch
// traffic). Barriers are lgkm-only (no vmcnt drain): no cross-wave global hazards exist
// (P stores write-only; K/V/mask loads consumed via register deps). Math identical to R2.

typedef __attribute__((ext_vector_type(8))) __bf16 bf16x8;
typedef __attribute__((ext_vector_type(4))) float f32x4;

#define L_SEQ 2048
#define D_H   128
#define R_Q   128     // q rows per block
#define C_K   64      // keys per k-tile
#define NTHR  512     // 8 waves
#define KPITCH 136    // shorts; 272 B row stride = 68 dwords (odd*4 -> conflict-free b128 reads)
#define VPITCH 72     // shorts; 144 B row stride
#define NKT   (L_SEQ / C_K)

__device__ __forceinline__ unsigned short f2bf(float f) {
    unsigned int u = __float_as_uint(f);
    unsigned int r = (u + 0x7FFFu + ((u >> 16) & 1u)) >> 16;  // RNE
    return (unsigned short)r;
}

__device__ __forceinline__ float fexp2(float x) {
#if __has_builtin(__builtin_amdgcn_exp2f)
    return __builtin_amdgcn_exp2f(x);
#else
    return exp2f(x);
#endif
}

__device__ __forceinline__ float rsum16(float v) {
#pragma unroll
    for (int o = 1; o < 16; o <<= 1) v += __shfl_xor(v, o, 64);
    return v;
}

// Raw workgroup barrier with LDS visibility but WITHOUT vmcnt drain.
// sched_barrier(0) on both sides pins all memory ops relative to the barrier;
// lgkmcnt(0) makes this wave's ds_writes visible; outstanding global loads/stores survive.
__device__ __forceinline__ void block_sync() {
    __builtin_amdgcn_sched_barrier(0);
    asm volatile("s_waitcnt lgkmcnt(0)");
    __builtin_amdgcn_s_barrier();
    __builtin_amdgcn_sched_barrier(0);
}

union BF8 {
    bf16x8 v;
    unsigned short s[8];
    uint4 u;
};

__global__ __launch_bounds__(NTHR, 4) void attn_kernel(
    const float* __restrict__ Q, const float* __restrict__ K,
    const float* __restrict__ V, const float* __restrict__ mask,
    const int* __restrict__ pad, float* __restrict__ Xout,
    float* __restrict__ Pout)
{
    __shared__ unsigned short Ks[C_K * KPITCH];   // 17408 B
    __shared__ unsigned short Vt[D_H * VPITCH];   // 18432 B (V transposed: [d][key])
    __shared__ unsigned short Ps[R_Q * VPITCH];   // 18432 B (wave-local C/D->A hop)
    __shared__ float PadB[L_SEQ];                 //  8192 B (0 or -inf)
    // total 62464 B -> 2 blocks/CU

    const int tid  = threadIdx.x;
    const int wave = tid >> 6;
    const int lane = tid & 63;
    const int quad = lane >> 4;
    const int l16  = lane & 15;

    const int bh = blockIdx.x & 31;   // same bh -> same XCD group for K/V L2 locality
    const int qt = blockIdx.x >> 5;
    const int b  = bh >> 4;

    const float LOG2E  = 1.44269504088896340736f;
    const float SCALE2 = 0.08838834764831845f * 1.44269504088896340736f;  // (1/sqrt(128))*log2e

    const float* Kg0 = K + (long long)bh * L_SEQ * D_H;
    const float* Vg0 = V + (long long)bh * L_SEQ * D_H;

    // ---- Q fragments straight to registers (A-layout: row=wave*16+l16, k=kb*32+quad*8+j) ----
    BF8 qf[4];
    {
        const float4* qrow = reinterpret_cast<const float4*>(
            Q + ((long long)bh * L_SEQ + qt * R_Q + wave * 16 + l16) * D_H);
#pragma unroll
        for (int kb = 0; kb < 4; ++kb) {
            float4 a = qrow[kb * 8 + quad * 2];
            float4 c = qrow[kb * 8 + quad * 2 + 1];
            qf[kb].s[0] = f2bf(a.x); qf[kb].s[1] = f2bf(a.y);
            qf[kb].s[2] = f2bf(a.z); qf[kb].s[3] = f2bf(a.w);
            qf[kb].s[4] = f2bf(c.x); qf[kb].s[5] = f2bf(c.y);
            qf[kb].s[6] = f2bf(c.z); qf[kb].s[7] = f2bf(c.w);
        }
    }
    // ---- padding bias (0 / -inf) ----
#pragma unroll
    for (int i = 0; i < 4; ++i) {
        int idx = tid + i * NTHR;
        PadB[idx] = pad[b * L_SEQ + idx] ? -INFINITY : 0.0f;
    }

    // ---- prefetch registers: loads for tile t+1 in flight under compute of tile t ----
    float4 kpre[4];    // 16 VGPR
    float  vpre[16];   // 16 VGPR (pass 2 only)

    auto issueK = [&](int kt) {
        const float4* Kg = reinterpret_cast<const float4*>(Kg0 + (long long)kt * C_K * D_H);
#pragma unroll
        for (int i = 0; i < 2; ++i) {
            int c = tid + i * NTHR;          // 8-float chunk id, 1024 total
            kpre[2 * i]     = Kg[c * 2];
            kpre[2 * i + 1] = Kg[c * 2 + 1];
        }
    };
    auto writeK = [&]() {
#pragma unroll
        for (int i = 0; i < 2; ++i) {
            int c = tid + i * NTHR;
            int row = c >> 4, off = (c & 15) * 8;
            float4 a = kpre[2 * i];
            float4 d = kpre[2 * i + 1];
            BF8 t;
            t.s[0] = f2bf(a.x); t.s[1] = f2bf(a.y); t.s[2] = f2bf(a.z); t.s[3] = f2bf(a.w);
            t.s[4] = f2bf(d.x); t.s[5] = f2bf(d.y); t.s[6] = f2bf(d.z); t.s[7] = f2bf(d.w);
            *reinterpret_cast<uint4*>(&Ks[row * KPITCH + off]) = t.u;   // 16B write
        }
    };
    auto issueV = [&](int kt) {
        const float* Vg = Vg0 + (long long)kt * C_K * D_H;
        int c = tid & 127;
#pragma unroll
        for (int i = 0; i < 2; ++i) {
            int key0 = (((tid >> 7) + i * 4) << 3);
#pragma unroll
            for (int j = 0; j < 8; ++j)
                vpre[i * 8 + j] = Vg[(key0 + j) * D_H + c];   // coalesced across lanes
        }
    };
    auto writeV = [&]() {
        int c = tid & 127;
#pragma unroll
        for (int i = 0; i < 2; ++i) {
            int key0 = (((tid >> 7) + i * 4) << 3);
            BF8 t;
#pragma unroll
            for (int j = 0; j < 8; ++j) t.s[j] = f2bf(vpre[i * 8 + j]);
            *reinterpret_cast<uint4*>(&Vt[c * VPITCH + key0]) = t.u;
        }
    };

    auto computeS = [&](f32x4* sacc) {
        f32x4 z4 = {0.f, 0.f, 0.f, 0.f};
#pragma unroll
        for (int ct = 0; ct < 4; ++ct) sacc[ct] = z4;
#pragma unroll
        for (int kb = 0; kb < 4; ++kb) {
#pragma unroll
            for (int ct = 0; ct < 4; ++ct) {
                bf16x8 bk = *reinterpret_cast<const bf16x8*>(
                    &Ks[(ct * 16 + l16) * KPITCH + kb * 32 + quad * 8]);
                sacc[ct] = __builtin_amdgcn_mfma_f32_16x16x32_bf16(qf[kb].v, bk, sacc[ct], 0, 0, 0);
            }
        }
    };

    // lane owns rows (quad*4 + r), r=0..3 (replicated over the 16 lanes of its quad)
    const long long qrow0 = (long long)(qt * R_Q + wave * 16 + quad * 4);
    const float* maskBase = mask + qrow0 * L_SEQ;

    // =================== PASS 1: row sums of exp2(e2) ===================
    float lpart[4] = {0.f, 0.f, 0.f, 0.f};
    issueK(0);
    writeK();                         // waits its own vmcnt via register dep
    for (int kt = 0; kt < NKT; ++kt) {
        block_sync();                 // (A) tile kt's LDS writes visible
        if (kt + 1 < NKT) issueK(kt + 1);   // in flight under compute below
        float mk[4][4], pb[4];
#pragma unroll
        for (int ct = 0; ct < 4; ++ct) {
            int kc = kt * C_K + ct * 16 + l16;
            pb[ct] = PadB[kc];
#pragma unroll
            for (int r = 0; r < 4; ++r) mk[ct][r] = maskBase[(long long)r * L_SEQ + kc];
        }
        f32x4 sacc[4];
        computeS(sacc);
#pragma unroll
        for (int ct = 0; ct < 4; ++ct)
#pragma unroll
            for (int r = 0; r < 4; ++r) {
                float m2 = fmaf(mk[ct][r], LOG2E, pb[ct]);          // -inf if padded
                float e2 = fmaf(sacc[ct][r], SCALE2, m2);
                lpart[r] += fexp2(e2);                              // exp2(-inf)=0
            }
        block_sync();                 // (B) all waves done reading tile kt
        if (kt + 1 < NKT) writeK();   // overwrite Ks with tile kt+1 (vmcnt wait here, covered)
    }

    float rinv[4];
#pragma unroll
    for (int r = 0; r < 4; ++r) {
        float l = rsum16(lpart[r]);
        rinv[r] = (l > 0.f) ? (1.0f / l) : 0.f;
    }

    // =================== PASS 2: write P, accumulate O = P @ V ===================
    f32x4 oacc[8];
    {
        f32x4 z4 = {0.f, 0.f, 0.f, 0.f};
#pragma unroll
        for (int ct = 0; ct < 8; ++ct) oacc[ct] = z4;
    }
    float* PoutBase = Pout + ((long long)bh * L_SEQ + (qt * R_Q + quad * 4 + wave * 16)) * L_SEQ;

    // pass1's final (B) barrier guarantees all waves are done reading Ks tile NKT-1.
    issueK(0);
    issueV(0);
    writeK();
    writeV();
    for (int kt = 0; kt < NKT; ++kt) {
        block_sync();                 // (A) tile kt's Ks/Vt writes visible
        if (kt + 1 < NKT) { issueK(kt + 1); issueV(kt + 1); }
        float mk[4][4], pb[4];
#pragma unroll
        for (int ct = 0; ct < 4; ++ct) {
            int kc = kt * C_K + ct * 16 + l16;
            pb[ct] = PadB[kc];
#pragma unroll
            for (int r = 0; r < 4; ++r) mk[ct][r] = maskBase[(long long)r * L_SEQ + kc];
        }
        f32x4 sacc[4];
        computeS(sacc);
#pragma unroll
        for (int ct = 0; ct < 4; ++ct) {
            int kc = kt * C_K + ct * 16 + l16;
#pragma unroll
            for (int r = 0; r < 4; ++r) {
                float m2 = fmaf(mk[ct][r], LOG2E, pb[ct]);
                float e2 = fmaf(sacc[ct][r], SCALE2, m2);
                float p  = fexp2(e2) * rinv[r];
                __builtin_nontemporal_store(p, &PoutBase[(long long)r * L_SEQ + kc]);
                Ps[(wave * 16 + quad * 4 + r) * VPITCH + ct * 16 + l16] = f2bf(p);
            }
        }
        // NO barrier: Ps rows [wave*16, wave*16+16) are written and read by the same wave;
        // in-wave DS ordering + compiler lgkmcnt handles the RAW.
#pragma unroll
        for (int kd = 0; kd < 2; ++kd) {
            bf16x8 ap = *reinterpret_cast<const bf16x8*>(
                &Ps[(wave * 16 + l16) * VPITCH + kd * 32 + quad * 8]);
#pragma unroll
            for (int ct = 0; ct < 8; ++ct) {
                bf16x8 bv = *reinterpret_cast<const bf16x8*>(
                    &Vt[(ct * 16 + l16) * VPITCH + kd * 32 + quad * 8]);
                oacc[ct] = __builtin_amdgcn_mfma_f32_16x16x32_bf16(ap, bv, oacc[ct], 0, 0, 0);
            }
        }
        block_sync();                 // (B) all waves done reading Ks/Vt tile kt
        if (kt + 1 < NKT) { writeK(); writeV(); }
    }

    // epilogue: O rows = quad*4+r, cols = ct*16+l16
    float* Xg = Xout + ((long long)bh * L_SEQ + qt * R_Q + wave * 16 + quad * 4) * D_H;
#pragma unroll
    for (int ct = 0; ct < 8; ++ct)
#pragma unroll
        for (int r = 0; r < 4; ++r)
            __builtin_nontemporal_store(oacc[ct][r], &Xg[r * D_H + ct * 16 + l16]);
}

extern "C" void kernel_launch(void* const* d_in, const int* in_sizes, int n_in,
                              void* d_out, int out_size, void* d_ws, size_t ws_size,
                              hipStream_t stream) {
    const float* Q    = (const float*)d_in[0];
    const float* K    = (const float*)d_in[1];
    const float* V    = (const float*)d_in[2];
    const float* mask = (const float*)d_in[3];
    const int*   pad  = (const int*)d_in[4];   // bool input -> int32 per harness dtype rules
    float* Xout = (float*)d_out;
    float* Pout = (float*)d_out + (long long)2 * 16 * 2048 * 128;  // x first, then attn weights
    attn_kernel<<<dim3(512), dim3(NTHR), 0, stream>>>(Q, K, V, mask, pad, Xout, Pout);
}